// Round 5
// baseline (331.561 us; speedup 1.0000x reference)
//
#include <hip/hip_runtime.h>

#define ZD 64
#define RD 128
#define HIDDEN 512
#define NSTEP 100
#define OUT_PITCH 6464              // 101*64
#define DT_F 0.01f
#define ROWS 16

static const size_t LW_OFF = 52953088ull;   // 8192*101*64
static const size_t NG_OFF = 52961280ull;   // + 8192

typedef __attribute__((ext_vector_type(2))) float  f32x2;
typedef __attribute__((ext_vector_type(4))) float  f32x4;
typedef __attribute__((ext_vector_type(8))) __bf16 bf16x8;
typedef __attribute__((ext_vector_type(2))) short  s16x2;
typedef __attribute__((ext_vector_type(4))) short  s16x4;
typedef __attribute__((ext_vector_type(8))) short  s16x8;

__device__ __forceinline__ short f2bs(float f) {
    return __builtin_bit_cast(short, (__bf16)f);
}
__device__ __forceinline__ float tanh_fast(float x) {
    float e = __builtin_amdgcn_exp2f(x * 2.88539008177793f);
    float r = __builtin_amdgcn_rcpf(e + 1.0f);
    return fmaf(-2.0f, r, 1.0f);
}

// ---------------------------------------------------------------------------
// sim_kernel: persistent scan. 512 blocks x 512 threads (8 waves), 16 rows.
// amdgpu_waves_per_eu(4,8): hard combined (VGPR+AGPR) cap of 128/wave so
// TWO 8-wave blocks co-reside per CU (R4's 1-block limiter was acc regs
// pushing combined past 128 while arch VGPR_Count=84 looked fine).
// pre = b1 + r@W1r computed in-init via MFMA. GEMM1: 8 waves x 4 n-tiles.
// GEMM2: 4 z-tiles x 2 K-halves -> Ps[2] partials, summed in update.
// x master state in update-thread registers.
// ---------------------------------------------------------------------------
__global__ __launch_bounds__(512)
__attribute__((amdgpu_waves_per_eu(4, 8)))
void sim_kernel(
    const float* __restrict__ r, const float* __restrict__ noises,
    const float* __restrict__ x0, const float* __restrict__ W1,
    const float* __restrict__ b1, const float* __restrict__ W2,
    const float* __restrict__ b2, const float* __restrict__ bmax,
    const float* __restrict__ bmin, const float* __restrict__ mu,
    float* __restrict__ out)
{
    __shared__ float Ps[2][ROWS][68];                 // 8704 B
    __shared__ unsigned short Xb[ROWS * 64];          // 2048 B
    __shared__ unsigned short Hs[ROWS * HIDDEN];      // 16384 B
    __shared__ float w1ts[HIDDEN];                    // 2048 B
    __shared__ float mus[ZD];                         // 256 B
    __shared__ float b2s[ZD];                         // 256 B
    __shared__ float tT[NSTEP], tG[NSTEP], tSd[NSTEP], tCd[NSTEP], tCs[NSTEP]; // 2000 B

    const int tid  = threadIdx.x;
    const int lane = tid & 63;
    const int wave = tid >> 6;
    const int g4   = lane >> 4;
    const int l16  = lane & 15;
    const int row0 = blockIdx.x * ROWS;

    // ---- step tables ----
    if (tid < NSTEP) {
        float spmax = log1pf(expf(bmax[0]));
        float spmin = log1pf(expf(bmin[0]));
        float a_ = spmax - spmin;
        float c_ = spmin;
        const float PI_ = 3.14159265358979323846f;
        float k = (float)tid;
        float t0 = k * DT_F, t1 = (k + 1.0f) * DT_F;
        float inv2pi = 1.0f / (2.0f * PI_);
        float F0 = a_ * sinf(PI_ * t0) * inv2pi + (0.5f * a_ + c_) * t0;
        float F1 = a_ * sinf(PI_ * t1) * inv2pi + (0.5f * a_ + c_) * t1;
        float al = 1.0f - expf(-2.0f * (F1 - F0));
        float gg = 1.0f - sqrtf(1.0f - al);
        float kap = (gg * gg) / al;
        tT[tid] = t0; tG[tid] = gg; tSd[tid] = sqrtf(al);
        tCd[tid] = -2.0f * kap; tCs[tid] = -2.0f * sqrtf(kap);
    }
    if (tid < HIDDEN) w1ts[tid] = W1[(size_t)192 * HIDDEN + tid];
    if (tid < ZD) { mus[tid] = mu[tid]; b2s[tid] = b2[tid]; }

    // ---- x state init (update-thread registers) + x_t[:,0,:] + Xb ----
    const int urow = tid >> 5;
    const int c2   = (tid & 31) * 2;
    const size_t ubase = (size_t)(row0 + urow);
    float xr0, xr1;
    {
        f32x2 v = *(const f32x2*)(x0 + ubase * ZD + c2);
        xr0 = v[0]; xr1 = v[1];
        *(f32x2*)(out + ubase * OUT_PITCH + c2) = v;
        s16x2 xv; xv[0] = f2bs(xr0); xv[1] = f2bs(xr1);
        *(s16x2*)(Xb + ((urow * 64 + c2) ^ ((urow & 7) << 3))) = xv;
    }

    // ---- pre-fragments via MFMA: pref = b1 + r @ W1r (bf16/f32-acc) ----
    f32x4 pref[4];
    {
        bf16x8 rf[4];
        const float* rp = r + (size_t)(row0 + l16) * RD;
        #pragma unroll
        for (int kc = 0; kc < 4; ++kc) {
            f32x4 lo = *(const f32x4*)(rp + kc * 32 + g4 * 8);
            f32x4 hi = *(const f32x4*)(rp + kc * 32 + g4 * 8 + 4);
            bf16x8 v;
            v[0]=(__bf16)lo[0]; v[1]=(__bf16)lo[1]; v[2]=(__bf16)lo[2]; v[3]=(__bf16)lo[3];
            v[4]=(__bf16)hi[0]; v[5]=(__bf16)hi[1]; v[6]=(__bf16)hi[2]; v[7]=(__bf16)hi[3];
            rf[kc] = v;
        }
        #pragma unroll
        for (int j2 = 0; j2 < 4; ++j2) {
            int n  = (wave * 4 + j2) * 16 + l16;
            int n0 = (wave * 4 + j2) * 16 + g4 * 4;
            f32x4 acc = *(const f32x4*)(b1 + n0);
            #pragma unroll
            for (int kc = 0; kc < 4; ++kc) {
                bf16x8 w;
                #pragma unroll
                for (int j = 0; j < 8; ++j)
                    w[j] = (__bf16)W1[(size_t)(64 + kc * 32 + g4 * 8 + j) * HIDDEN + n];
                acc = __builtin_amdgcn_mfma_f32_16x16x32_bf16(w, rf[kc], acc, 0, 0, 0);
            }
            pref[j2] = acc;
        }
    }

    // ---- persistent weight fragments ----
    bf16x8 w1f[4][2];
    #pragma unroll
    for (int j2 = 0; j2 < 4; ++j2) {
        int n = (wave * 4 + j2) * 16 + l16;
        #pragma unroll
        for (int kc = 0; kc < 2; ++kc) {
            bf16x8 v;
            #pragma unroll
            for (int j = 0; j < 8; ++j) {
                int kk = kc * 32 + g4 * 8 + j;
                v[j] = (__bf16)W1[(size_t)kk * HIDDEN + n];
            }
            w1f[j2][kc] = v;
        }
    }
    // GEMM2: wave -> (kh = wave>>2 in 0..1, zt = wave&3 in 0..3)
    const int kh = wave >> 2, zt = wave & 3;
    bf16x8 w2f[8];
    {
        int n = zt * 16 + l16;
        #pragma unroll
        for (int i = 0; i < 8; ++i) {
            int kc = kh * 8 + i;
            bf16x8 v;
            #pragma unroll
            for (int j = 0; j < 8; ++j) {
                int kk = kc * 32 + g4 * 8 + j;
                v[j] = (__bf16)W2[(size_t)kk * ZD + n];
            }
            w2f[i] = v;
        }
    }

    float lw_acc = 0.0f;
    const int xswz = (l16 & 7) << 3;

    __syncthreads();

    for (int s = 0; s < NSTEP; ++s) {
        float t = tT[s], gg = tG[s], sdv = tSd[s], cd = tCd[s], cs = tCs[s];
        // noise prefetch for update phase (hidden under 2 barriers)
        f32x2 nz = *(const f32x2*)(noises + (ubase * NSTEP + s) * ZD + c2);

        // ================= GEMM1: h = tanh(x@W1x + pre + t*w1t) ============
        s16x8 xb0 = *(const s16x8*)(Xb + ((l16 * 64 + g4 * 8) ^ xswz));
        s16x8 xb1 = *(const s16x8*)(Xb + ((l16 * 64 + 32 + g4 * 8) ^ xswz));
        #pragma unroll
        for (int j2 = 0; j2 < 4; ++j2) {
            int n0 = (wave * 4 + j2) * 16 + g4 * 4;
            f32x4 wt = *(const f32x4*)(w1ts + n0);
            f32x4 acc = pref[j2];
            acc[0] = fmaf(t, wt[0], acc[0]);
            acc[1] = fmaf(t, wt[1], acc[1]);
            acc[2] = fmaf(t, wt[2], acc[2]);
            acc[3] = fmaf(t, wt[3], acc[3]);
            acc = __builtin_amdgcn_mfma_f32_16x16x32_bf16(
                w1f[j2][0], __builtin_bit_cast(bf16x8, xb0), acc, 0, 0, 0);
            acc = __builtin_amdgcn_mfma_f32_16x16x32_bf16(
                w1f[j2][1], __builtin_bit_cast(bf16x8, xb1), acc, 0, 0, 0);
            s16x4 hv;
            hv[0] = f2bs(tanh_fast(acc[0]));
            hv[1] = f2bs(tanh_fast(acc[1]));
            hv[2] = f2bs(tanh_fast(acc[2]));
            hv[3] = f2bs(tanh_fast(acc[3]));
            *(s16x4*)(Hs + ((l16 * HIDDEN + n0) ^ xswz)) = hv;
        }
        __syncthreads();

        // ====== GEMM2 (z-tile x K-half): partials -> Ps[kh] ================
        {
            f32x4 accA = { 0.f, 0.f, 0.f, 0.f };
            f32x4 accB = { 0.f, 0.f, 0.f, 0.f };
            int base = l16 * HIDDEN + kh * 256 + g4 * 8;
            #pragma unroll
            for (int i = 0; i < 8; i += 2) {
                s16x8 h0 = *(const s16x8*)(Hs + ((base + i * 32) ^ xswz));
                accA = __builtin_amdgcn_mfma_f32_16x16x32_bf16(
                    w2f[i], __builtin_bit_cast(bf16x8, h0), accA, 0, 0, 0);
                s16x8 h1 = *(const s16x8*)(Hs + ((base + (i + 1) * 32) ^ xswz));
                accB = __builtin_amdgcn_mfma_f32_16x16x32_bf16(
                    w2f[i + 1], __builtin_bit_cast(bf16x8, h1), accB, 0, 0, 0);
            }
            accA[0] += accB[0]; accA[1] += accB[1];
            accA[2] += accB[2]; accA[3] += accB[3];
            *(f32x4*)(&Ps[kh][l16][zt * 16 + g4 * 4]) = accA;
        }
        __syncthreads();

        // ================= Update (x in registers) =========================
        {
            f32x2 p0 = *(const f32x2*)(&Ps[0][urow][c2]);
            f32x2 p1 = *(const f32x2*)(&Ps[1][urow][c2]);
            f32x2 bb = *(const f32x2*)(&b2s[c2]);
            float s0 = p0[0] + p1[0] + bb[0];
            float s1 = p0[1] + p1[1] + bb[1];
            float xn0 = xr0 + gg * (2.0f * s0 - xr0) + sdv * nz[0];
            float xn1 = xr1 + gg * (2.0f * s1 - xr1) + sdv * nz[1];
            xr0 = xn0; xr1 = xn1;
            f32x2 xv = { xn0, xn1 };
            *(f32x2*)(out + ubase * OUT_PITCH + (size_t)(s + 1) * ZD + c2) = xv;
            s16x2 xb2; xb2[0] = f2bs(xn0); xb2[1] = f2bs(xn1);
            *(s16x2*)(Xb + ((urow * 64 + c2) ^ ((urow & 7) << 3))) = xb2;
            float v = cd * (s0 * s0 + s1 * s1) + cs * (s0 * nz[0] + s1 * nz[1]);
            v += __shfl_xor(v, 1, 64);
            v += __shfl_xor(v, 2, 64);
            v += __shfl_xor(v, 4, 64);
            v += __shfl_xor(v, 8, 64);
            v += __shfl_xor(v, 16, 64);
            lw_acc += v;
        }
        __syncthreads();
    }

    // ---- finalize: log_weights and nabla_g ----
    {
        float m0 = mus[c2], m1 = mus[c2 + 1];
        float d0 = xr0 - m0, d1 = xr1 - m1;
        f32x2 ng = { d0 - xr0, d1 - xr1 };           // == -mu
        *(f32x2*)(out + NG_OFF + ubase * ZD + c2) = ng;
        float part = 0.5f * (xr0 * xr0 + xr1 * xr1) - 0.5f * (d0 * d0 + d1 * d1);
        part += __shfl_xor(part, 1, 64);
        part += __shfl_xor(part, 2, 64);
        part += __shfl_xor(part, 4, 64);
        part += __shfl_xor(part, 8, 64);
        part += __shfl_xor(part, 16, 64);
        if ((tid & 31) == 0) out[LW_OFF + ubase] = lw_acc + part;
    }
}

extern "C" void kernel_launch(void* const* d_in, const int* in_sizes, int n_in,
                              void* d_out, int out_size, void* d_ws, size_t ws_size,
                              hipStream_t stream) {
    const float* r      = (const float*)d_in[0];
    const float* noises = (const float*)d_in[1];
    const float* x0     = (const float*)d_in[2];
    const float* W1     = (const float*)d_in[3];
    const float* b1     = (const float*)d_in[4];
    const float* W2     = (const float*)d_in[5];
    const float* b2     = (const float*)d_in[6];
    const float* bmax   = (const float*)d_in[7];
    const float* bmin   = (const float*)d_in[8];
    const float* mu     = (const float*)d_in[9];
    float* out = (float*)d_out;

    sim_kernel<<<512, 512, 0, stream>>>(r, noises, x0, W1, b1, W2, b2,
                                        bmax, bmin, mu, out);
}

// Round 6
// 260.808 us; speedup vs baseline: 1.2713x; 1.2713x over previous
//
#include <hip/hip_runtime.h>

#define ZD 64
#define RD 128
#define HIDDEN 512
#define NSTEP 100
#define OUT_PITCH 6464              // 101*64
#define DT_F 0.01f
#define ROWS 32

static const size_t LW_OFF = 52953088ull;   // 8192*101*64
static const size_t NG_OFF = 52961280ull;   // + 8192

typedef __attribute__((ext_vector_type(2))) float  f32x2;
typedef __attribute__((ext_vector_type(4))) float  f32x4;
typedef __attribute__((ext_vector_type(8))) __bf16 bf16x8;
typedef __attribute__((ext_vector_type(2))) short  s16x2;
typedef __attribute__((ext_vector_type(4))) short  s16x4;
typedef __attribute__((ext_vector_type(8))) short  s16x8;

__device__ __forceinline__ short f2bs(float f) {
    return __builtin_bit_cast(short, (__bf16)f);
}
__device__ __forceinline__ float tanh_fast(float x) {
    float e = __builtin_amdgcn_exp2f(x * 2.88539008177793f);
    float r = __builtin_amdgcn_rcpf(e + 1.0f);
    return fmaf(-2.0f, r, 1.0f);
}

// ---------------------------------------------------------------------------
// sim_kernel: persistent scan. 256 blocks x 1024 threads (16 waves), 32 rows
// per block = exactly 1 block/CU, no sequential rounds. 16-wave split keeps
// per-wave persistent regs at ~70 (w1f 16 + pref 16 + w2f 32) so combined
// VGPR+AGPR fits the 128 cap -> 4 waves/SIMD, no spills.
// GEMM1: wave -> 2 n-tiles x 2 m-tiles. GEMM2: wave -> (zt, K-half, m-tile).
// x master state in update-thread registers; bf16 copy Xb feeds GEMM1.
// ---------------------------------------------------------------------------
__global__ __launch_bounds__(1024, 1)
void sim_kernel(
    const float* __restrict__ r, const float* __restrict__ noises,
    const float* __restrict__ x0, const float* __restrict__ W1,
    const float* __restrict__ b1, const float* __restrict__ W2,
    const float* __restrict__ b2, const float* __restrict__ bmax,
    const float* __restrict__ bmin, const float* __restrict__ mu,
    float* __restrict__ out)
{
    __shared__ float Ps[2][ROWS][68];                 // 17408 B
    __shared__ unsigned short Xb[ROWS * 64];          // 4096 B
    __shared__ unsigned short Hs[ROWS * HIDDEN];      // 32768 B
    __shared__ float w1ts[HIDDEN];                    // 2048 B
    __shared__ float mus[ZD];                         // 256 B
    __shared__ float b2s[ZD];                         // 256 B
    __shared__ float tT[NSTEP], tG[NSTEP], tSd[NSTEP], tCd[NSTEP], tCs[NSTEP]; // 2000 B

    const int tid  = threadIdx.x;
    const int lane = tid & 63;
    const int wave = tid >> 6;       // 0..15
    const int g4   = lane >> 4;      // 0..3
    const int l16  = lane & 15;
    const int row0 = blockIdx.x * ROWS;

    // ---- step tables ----
    if (tid < NSTEP) {
        float spmax = log1pf(expf(bmax[0]));
        float spmin = log1pf(expf(bmin[0]));
        float a_ = spmax - spmin;
        float c_ = spmin;
        const float PI_ = 3.14159265358979323846f;
        float k = (float)tid;
        float t0 = k * DT_F, t1 = (k + 1.0f) * DT_F;
        float inv2pi = 1.0f / (2.0f * PI_);
        float F0 = a_ * sinf(PI_ * t0) * inv2pi + (0.5f * a_ + c_) * t0;
        float F1 = a_ * sinf(PI_ * t1) * inv2pi + (0.5f * a_ + c_) * t1;
        float al = 1.0f - expf(-2.0f * (F1 - F0));
        float gg = 1.0f - sqrtf(1.0f - al);
        float kap = (gg * gg) / al;
        tT[tid] = t0; tG[tid] = gg; tSd[tid] = sqrtf(al);
        tCd[tid] = -2.0f * kap; tCs[tid] = -2.0f * sqrtf(kap);
    }
    if (tid < HIDDEN) w1ts[tid] = W1[(size_t)192 * HIDDEN + tid];
    if (tid < ZD) { mus[tid] = mu[tid]; b2s[tid] = b2[tid]; }

    // ---- x state init (update-thread registers) + x_t[:,0,:] + Xb ----
    const int urow = tid >> 5;          // 0..31
    const int c2   = (tid & 31) * 2;    // 0..62
    const size_t ubase = (size_t)(row0 + urow);
    float xr0, xr1;
    {
        f32x2 v = *(const f32x2*)(x0 + ubase * ZD + c2);
        xr0 = v[0]; xr1 = v[1];
        *(f32x2*)(out + ubase * OUT_PITCH + c2) = v;
        s16x2 xv; xv[0] = f2bs(xr0); xv[1] = f2bs(xr1);
        *(s16x2*)(Xb + ((urow * 64 + c2) ^ ((urow & 7) << 3))) = xv;
    }

    // ---- pre-fragments via MFMA: pref[j2][mt] = b1 + r @ W1r ----
    f32x4 pref[2][2];
    {
        #pragma unroll
        for (int mt = 0; mt < 2; ++mt) {
            bf16x8 rf[4];
            const float* rp = r + (size_t)(row0 + mt * 16 + l16) * RD;
            #pragma unroll
            for (int kc = 0; kc < 4; ++kc) {
                f32x4 lo = *(const f32x4*)(rp + kc * 32 + g4 * 8);
                f32x4 hi = *(const f32x4*)(rp + kc * 32 + g4 * 8 + 4);
                bf16x8 v;
                v[0]=(__bf16)lo[0]; v[1]=(__bf16)lo[1]; v[2]=(__bf16)lo[2]; v[3]=(__bf16)lo[3];
                v[4]=(__bf16)hi[0]; v[5]=(__bf16)hi[1]; v[6]=(__bf16)hi[2]; v[7]=(__bf16)hi[3];
                rf[kc] = v;
            }
            #pragma unroll
            for (int j2 = 0; j2 < 2; ++j2) {
                int n  = (wave * 2 + j2) * 16 + l16;
                int n0 = (wave * 2 + j2) * 16 + g4 * 4;
                f32x4 acc = *(const f32x4*)(b1 + n0);
                #pragma unroll
                for (int kc = 0; kc < 4; ++kc) {
                    bf16x8 w;
                    #pragma unroll
                    for (int j = 0; j < 8; ++j)
                        w[j] = (__bf16)W1[(size_t)(64 + kc * 32 + g4 * 8 + j) * HIDDEN + n];
                    acc = __builtin_amdgcn_mfma_f32_16x16x32_bf16(w, rf[kc], acc, 0, 0, 0);
                }
                pref[j2][mt] = acc;
            }
        }
    }

    // ---- persistent weight fragments ----
    bf16x8 w1f[2][2];                // [j2][kc]
    #pragma unroll
    for (int j2 = 0; j2 < 2; ++j2) {
        int n = (wave * 2 + j2) * 16 + l16;
        #pragma unroll
        for (int kc = 0; kc < 2; ++kc) {
            bf16x8 v;
            #pragma unroll
            for (int j = 0; j < 8; ++j) {
                int kk = kc * 32 + g4 * 8 + j;
                v[j] = (__bf16)W1[(size_t)kk * HIDDEN + n];
            }
            w1f[j2][kc] = v;
        }
    }
    // GEMM2 wave role: zt = wave&3, kh = (wave>>2)&1, mt2 = wave>>3
    const int zt = wave & 3, kh = (wave >> 2) & 1, mt2 = wave >> 3;
    bf16x8 w2f[8];
    {
        int n = zt * 16 + l16;
        #pragma unroll
        for (int i = 0; i < 8; ++i) {
            int kc = kh * 8 + i;
            bf16x8 v;
            #pragma unroll
            for (int j = 0; j < 8; ++j) {
                int kk = kc * 32 + g4 * 8 + j;
                v[j] = (__bf16)W2[(size_t)kk * ZD + n];
            }
            w2f[i] = v;
        }
    }

    float lw_acc = 0.0f;

    __syncthreads();

    for (int s = 0; s < NSTEP; ++s) {
        float t = tT[s], gg = tG[s], sdv = tSd[s], cd = tCd[s], cs = tCs[s];
        // noise prefetch for update phase (hidden under 2 barriers)
        f32x2 nz = *(const f32x2*)(noises + (ubase * NSTEP + s) * ZD + c2);

        // ================= GEMM1: h = tanh(x@W1x + pre + t*w1t) ============
        {
            s16x8 xb[2][2];
            #pragma unroll
            for (int mt = 0; mt < 2; ++mt) {
                int m = mt * 16 + l16;
                int swz = (m & 7) << 3;
                xb[mt][0] = *(const s16x8*)(Xb + ((m * 64 + g4 * 8) ^ swz));
                xb[mt][1] = *(const s16x8*)(Xb + ((m * 64 + 32 + g4 * 8) ^ swz));
            }
            #pragma unroll
            for (int j2 = 0; j2 < 2; ++j2) {
                int n0 = (wave * 2 + j2) * 16 + g4 * 4;
                f32x4 wt = *(const f32x4*)(w1ts + n0);
                #pragma unroll
                for (int mt = 0; mt < 2; ++mt) {
                    f32x4 acc = pref[j2][mt];
                    acc[0] = fmaf(t, wt[0], acc[0]);
                    acc[1] = fmaf(t, wt[1], acc[1]);
                    acc[2] = fmaf(t, wt[2], acc[2]);
                    acc[3] = fmaf(t, wt[3], acc[3]);
                    acc = __builtin_amdgcn_mfma_f32_16x16x32_bf16(
                        w1f[j2][0], __builtin_bit_cast(bf16x8, xb[mt][0]), acc, 0, 0, 0);
                    acc = __builtin_amdgcn_mfma_f32_16x16x32_bf16(
                        w1f[j2][1], __builtin_bit_cast(bf16x8, xb[mt][1]), acc, 0, 0, 0);
                    s16x4 hv;
                    hv[0] = f2bs(tanh_fast(acc[0]));
                    hv[1] = f2bs(tanh_fast(acc[1]));
                    hv[2] = f2bs(tanh_fast(acc[2]));
                    hv[3] = f2bs(tanh_fast(acc[3]));
                    int m = mt * 16 + l16;
                    *(s16x4*)(Hs + ((m * HIDDEN + n0) ^ ((m & 7) << 3))) = hv;
                }
            }
        }
        __syncthreads();

        // ====== GEMM2 (zt x K-half x m-tile): partials -> Ps[kh] ===========
        {
            int m = mt2 * 16 + l16;
            int swz = (m & 7) << 3;
            f32x4 accA = { 0.f, 0.f, 0.f, 0.f };
            f32x4 accB = { 0.f, 0.f, 0.f, 0.f };
            int base = m * HIDDEN + kh * 256 + g4 * 8;
            #pragma unroll
            for (int i = 0; i < 8; i += 2) {
                s16x8 h0 = *(const s16x8*)(Hs + ((base + i * 32) ^ swz));
                accA = __builtin_amdgcn_mfma_f32_16x16x32_bf16(
                    w2f[i], __builtin_bit_cast(bf16x8, h0), accA, 0, 0, 0);
                s16x8 h1 = *(const s16x8*)(Hs + ((base + (i + 1) * 32) ^ swz));
                accB = __builtin_amdgcn_mfma_f32_16x16x32_bf16(
                    w2f[i + 1], __builtin_bit_cast(bf16x8, h1), accB, 0, 0, 0);
            }
            accA[0] += accB[0]; accA[1] += accB[1];
            accA[2] += accB[2]; accA[3] += accB[3];
            *(f32x4*)(&Ps[kh][m][zt * 16 + g4 * 4]) = accA;
        }
        __syncthreads();

        // ================= Update (x in registers) =========================
        {
            f32x2 p0 = *(const f32x2*)(&Ps[0][urow][c2]);
            f32x2 p1 = *(const f32x2*)(&Ps[1][urow][c2]);
            f32x2 bb = *(const f32x2*)(&b2s[c2]);
            float s0 = p0[0] + p1[0] + bb[0];
            float s1 = p0[1] + p1[1] + bb[1];
            float xn0 = xr0 + gg * (2.0f * s0 - xr0) + sdv * nz[0];
            float xn1 = xr1 + gg * (2.0f * s1 - xr1) + sdv * nz[1];
            xr0 = xn0; xr1 = xn1;
            f32x2 xv = { xn0, xn1 };
            *(f32x2*)(out + ubase * OUT_PITCH + (size_t)(s + 1) * ZD + c2) = xv;
            s16x2 xb2; xb2[0] = f2bs(xn0); xb2[1] = f2bs(xn1);
            *(s16x2*)(Xb + ((urow * 64 + c2) ^ ((urow & 7) << 3))) = xb2;
            float v = cd * (s0 * s0 + s1 * s1) + cs * (s0 * nz[0] + s1 * nz[1]);
            v += __shfl_xor(v, 1, 64);
            v += __shfl_xor(v, 2, 64);
            v += __shfl_xor(v, 4, 64);
            v += __shfl_xor(v, 8, 64);
            v += __shfl_xor(v, 16, 64);
            lw_acc += v;
        }
        __syncthreads();
    }

    // ---- finalize: log_weights and nabla_g ----
    {
        float m0 = mus[c2], m1 = mus[c2 + 1];
        float d0 = xr0 - m0, d1 = xr1 - m1;
        f32x2 ng = { d0 - xr0, d1 - xr1 };           // == -mu
        *(f32x2*)(out + NG_OFF + ubase * ZD + c2) = ng;
        float part = 0.5f * (xr0 * xr0 + xr1 * xr1) - 0.5f * (d0 * d0 + d1 * d1);
        part += __shfl_xor(part, 1, 64);
        part += __shfl_xor(part, 2, 64);
        part += __shfl_xor(part, 4, 64);
        part += __shfl_xor(part, 8, 64);
        part += __shfl_xor(part, 16, 64);
        if ((tid & 31) == 0) out[LW_OFF + ubase] = lw_acc + part;
    }
}

extern "C" void kernel_launch(void* const* d_in, const int* in_sizes, int n_in,
                              void* d_out, int out_size, void* d_ws, size_t ws_size,
                              hipStream_t stream) {
    const float* r      = (const float*)d_in[0];
    const float* noises = (const float*)d_in[1];
    const float* x0     = (const float*)d_in[2];
    const float* W1     = (const float*)d_in[3];
    const float* b1     = (const float*)d_in[4];
    const float* W2     = (const float*)d_in[5];
    const float* b2     = (const float*)d_in[6];
    const float* bmax   = (const float*)d_in[7];
    const float* bmin   = (const float*)d_in[8];
    const float* mu     = (const float*)d_in[9];
    float* out = (float*)d_out;

    sim_kernel<<<256, 1024, 0, stream>>>(r, noises, x0, W1, b1, W2, b2,
                                         bmax, bmin, mu, out);
}